// Round 11
// baseline (265.036 us; speedup 1.0000x reference)
//
#include <hip/hip_runtime.h>
#include <hip/hip_bf16.h>
#include <cstdint>
#include <cstddef>

#define B_N 4096
typedef short short8 __attribute__((ext_vector_type(8)));
typedef float f32x4 __attribute__((ext_vector_type(4)));

// ws layout (float units)
static constexpr size_t H2B_OFF    = 0;                                  // 4096*4096 ushort
static constexpr size_t POOLED_OFF = 8388608;                            // (unused)
static constexpr size_t EIDX_OFF   = POOLED_OFF + (size_t)B_N * 16;      // B int
static constexpr size_t EW_OFF     = EIDX_OFF + B_N;                     // B f
static constexpr size_t ORDER_OFF  = EW_OFF + B_N;                       // 4*B int
static constexpr size_t CNT_OFF    = ORDER_OFF + (size_t)4 * B_N;        // 4 int
static constexpr size_t PSUM_OFF   = CNT_OFF + 4;
static constexpr size_t W2R_OFF    = PSUM_OFF + 4;                       // 73728 ushort
static constexpr size_t W1R_OFF    = W2R_OFF + 36864;                    // 2097152 ushort
static constexpr size_t W1C_OFF    = W1R_OFF + 1048576;                  // 4096 ushort

__device__ __forceinline__ unsigned int f2bf(float f) {
  unsigned int u = __float_as_uint(f);
  return (u + 0x7fffu + ((u >> 16) & 1u)) >> 16;   // RNE bf16
}
__device__ __forceinline__ unsigned int pkbf(float lo, float hi) {
  float2 f; f.x = lo; f.y = hi;
  __hip_bfloat162 b = __float22bfloat162_rn(f);     // v_cvt_pk_bf16_f32
  union { __hip_bfloat162 b; unsigned u; } c; c.b = b; return c.u;
}

// ---------------- K1: router conv (R0 path, fp32, SGPR weights) + per-sample FC/softmax/top1
// tail, MERGED with weight repacks. Ledger lesson (R5-R10): the router belongs in this
// kernel's PARALLEL 4096-block path (~25 us at full occupancy), not on conv's serial
// critical path (+57 us there). The per-sample FC tail needs no extra launch; bucketing
// (counts/order) moves to conv's t0 so counts zeroing here is race-free (cross-kernel).
__global__ __launch_bounds__(256) void k_front(const float* __restrict__ x,
    const float* __restrict__ gw, const float* __restrict__ gb,
    const float* __restrict__ gwfc, const float* __restrict__ gbfc,
    const float* __restrict__ wfc1, unsigned short* __restrict__ w1r,
    const float* __restrict__ wc2, unsigned short* __restrict__ w2r,
    const float* __restrict__ wc1, unsigned short* __restrict__ w1c,
    int* __restrict__ counts, float* __restrict__ probs_out,
    float* __restrict__ ewt, int* __restrict__ eidx) {
  __shared__ __align__(16) float xpad[3 * 34 * 34];   // 13872 B (rc path only)
  __shared__ float red[16 * 33];
  __shared__ float pooled_s[16];
  const int bid = blockIdx.x, t = threadIdx.x;
  if (bid >= 4096) {            // ---- repack paths ----
    const int rb = bid - 4096;
    if (rb < 2048) {
      const int i = rb * 256 + t;                    // float4 index
      const float4 v = ((const float4*)wfc1)[i];
      ushort4 u;
      u.x = (unsigned short)f2bf(v.x); u.y = (unsigned short)f2bf(v.y);
      u.z = (unsigned short)f2bf(v.z); u.w = (unsigned short)f2bf(v.w);
      *(ushort4*)(w1r + 4 * (size_t)i) = u;
    } else if (rb < 2336) {
      if (rb == 2048 && t < 8) counts[t] = 0;        // counts: consumed by conv (next kernel)
      const int i = (rb - 2048) * 256 + t;
      if (i < 4 * 9 * 64 * 32) {
        const int ic = i & 31, j = i >> 5;
        const int oc = j & 63, j2 = j >> 6;
        const int s = j2 % 9, e = j2 / 9;
        w2r[i] = (unsigned short)f2bf(wc2[(((size_t)e * 64 + oc) * 32 + ic) * 9 + s]);
      }
    } else {
      const int i = (rb - 2336) * 256 + t;           // [0, 4096)
      if (i < 4096) {
        const int j = i & 7, n16 = (i >> 3) & 15, q = (i >> 7) & 3, nt = (i >> 9) & 1, e = i >> 10;
        const int k = q * 8 + j;
        float v = 0.f;
        if (k < 27) {
          const int ky = k / 9, c = k % 9, kx = c / 3, ic = c % 3;
          v = wc1[((e * 32 + nt * 16 + n16) * 3 + ic) * 9 + ky * 3 + kx];
        }
        w1c[i] = (unsigned short)f2bf(v);
      }
    }
    return;
  }
  // ---- router conv path (verbatim R0) ----
  const int b = bid;
  for (int i = t; i < 867; i += 256) ((uint4*)xpad)[i] = make_uint4(0, 0, 0, 0);
  __syncthreads();
  const float4* x4 = (const float4*)(x + (size_t)b * 3072);
  for (int i = t; i < 768; i += 256) {
    float4 v = x4[i];
    int flat = i * 4, ic = flat >> 10, rem = flat & 1023, row = rem >> 5, col = rem & 31;
    float* d = &xpad[ic * 1156 + (row + 1) * 34 + (col + 1)];
    d[0] = v.x; d[1] = v.y; d[2] = v.z; d[3] = v.w;
  }
  __syncthreads();
  const int ty = t >> 4, tx = t & 15;
  float win[3][4][4];
#pragma unroll
  for (int ic = 0; ic < 3; ++ic)
#pragma unroll
  for (int rr = 0; rr < 4; ++rr) {
    const float2* p = (const float2*)&xpad[ic * 1156 + (2 * ty + rr) * 34 + 2 * tx];
    float2 a = p[0], c = p[1];
    win[ic][rr][0] = a.x; win[ic][rr][1] = a.y; win[ic][rr][2] = c.x; win[ic][rr][3] = c.y;
  }
  float sums[16];
#pragma unroll
  for (int oc = 0; oc < 16; ++oc) {
    const float bias = gb[oc];
    float a00 = bias, a01 = bias, a10 = bias, a11 = bias;
#pragma unroll
    for (int ic = 0; ic < 3; ++ic)
#pragma unroll
    for (int ky = 0; ky < 3; ++ky)
#pragma unroll
    for (int kx = 0; kx < 3; ++kx) {
      const float wv = gw[oc * 27 + ic * 9 + ky * 3 + kx];   // block-uniform -> SGPR
      a00 += wv * win[ic][ky][kx];     a01 += wv * win[ic][ky][kx + 1];
      a10 += wv * win[ic][ky + 1][kx]; a11 += wv * win[ic][ky + 1][kx + 1];
    }
    sums[oc] = fmaxf(a00, 0.f) + fmaxf(a01, 0.f) + fmaxf(a10, 0.f) + fmaxf(a11, 0.f);
  }
  const int lane = t & 63, wid = t >> 6;
#pragma unroll
  for (int oc = 0; oc < 16; ++oc) {
    float s = sums[oc];
    s += __shfl_xor(s, 1);
    s += __shfl_xor(s, 2);
    s += __shfl_xor(s, 4);
    sums[oc] = s;
  }
  if ((lane & 7) == 0) {
    const int slot = wid * 8 + (lane >> 3);
#pragma unroll
    for (int oc = 0; oc < 16; ++oc) red[oc * 33 + slot] = sums[oc];
  }
  __syncthreads();
  if (t < 16) {
    float s = 0.f;
#pragma unroll
    for (int i = 0; i < 32; ++i) s += red[t * 33 + i];
    pooled_s[t] = s * (1.f / 1024.f);
  }
  __syncthreads();
  if (t == 0) {   // verbatim per-sample router FC + softmax + top1 (R5 tail)
    float l[4];
#pragma unroll
    for (int j = 0; j < 4; ++j) {
      float s = gbfc[j];
#pragma unroll
      for (int i = 0; i < 16; ++i) s += pooled_s[i] * gwfc[j * 16 + i];
      l[j] = s;
    }
    const float mx = fmaxf(fmaxf(l[0], l[1]), fmaxf(l[2], l[3]));
    float ex[4], ssum = 0.f;
#pragma unroll
    for (int j = 0; j < 4; ++j) { ex[j] = expf(l[j] - mx); ssum += ex[j]; }
    const float inv = 1.f / ssum;
    float p[4];
#pragma unroll
    for (int j = 0; j < 4; ++j) p[j] = ex[j] * inv;
    *(float4*)(probs_out + (size_t)b * 4) = make_float4(p[0], p[1], p[2], p[3]);
    int em = 0; float pm = p[0];
#pragma unroll
    for (int j = 1; j < 4; ++j) if (p[j] > pm) { pm = p[j]; em = j; }
    ewt[b] = pm;
    eidx[b] = em;
  }
}

// ---- conv1 A-fragment gather from ic-interleaved fp32 image (packed bf16 cvt) ----
__device__ __forceinline__ short8 gather_a(const float* __restrict__ base,
                                           const int* goff, bool isq1, bool isq3) {
  const float a0 = base[goff[0]];
  float       a1 = base[goff[0] + 1];
  const float b0 = base[goff[1]], b1 = base[goff[1] + 1];
  const float c0 = base[goff[2]], c1 = base[goff[2] + 1];
  const float d0 = base[goff[3]], d1 = base[goff[3] + 1];
  a1 = isq1 ? base[102] : a1;          // patch: p=9 (row 1, c 0) for q==1 lanes
  union { unsigned u[4]; short8 s; } r;
  r.u[0] = pkbf(a0, a1);
  r.u[1] = pkbf(b0, isq3 ? 0.f : b1);  // p>=27 zero padding (q==3)
  r.u[2] = isq3 ? 0u : pkbf(c0, c1);
  r.u[3] = isq3 ? 0u : pkbf(d0, d1);
  return r.s;
}

// ---------------- K3: conv1 MFMA (im2col) -> h1 bf16 LDS -> conv2 MFMA -> h2 bf16 ----------------
// Verbatim R0 69-us body + t0 bucketing (counts/order atomicAdd moved here from the
// router; runs strictly between k_front (producer of eidx/counts-zero) and k_fc
// (consumer) -> race-free by kernel boundaries).
__global__ __launch_bounds__(256, 3) void k_experts_conv(const float* __restrict__ x,
    const unsigned short* __restrict__ w1c, const float* __restrict__ b1g,
    const unsigned short* __restrict__ w2r, const float* __restrict__ b2g,
    const int* __restrict__ eidx, unsigned short* __restrict__ h2b,
    int* __restrict__ counts, int* __restrict__ order) {
  __shared__ __align__(16) float xpi[3572];                  // 14288 B
  __shared__ __align__(16) unsigned short h1s[18 * 18 * 36]; // 23328 B
  const int b = blockIdx.x, t = threadIdx.x;
  const int e = __builtin_amdgcn_readfirstlane(eidx[b]);
  if (t == 0) {                         // bucketing (was in router)
    const int slot = atomicAdd(&counts[e], 1);
    order[e * B_N + slot] = b;
  }
  {
    uint4 z4 = make_uint4(0, 0, 0, 0);
    uint4* z1 = (uint4*)h1s;
    for (int i = t; i < 1458; i += 256) z1[i] = z4;
    uint4* z2 = (uint4*)xpi;
    for (int i = t; i < 893; i += 256) z2[i] = z4;
  }
  __syncthreads();
  const float4* x4 = (const float4*)(x + (size_t)b * 3072);
  for (int i = t; i < 768; i += 256) {
    float4 v = x4[i];
    int flat = i * 4, ic = flat >> 10, rem = flat & 1023, row = rem >> 5, col = rem & 31;
    float* d = &xpi[(row + 1) * 102 + (col + 1) * 3 + ic];
    d[0] = v.x; d[3] = v.y; d[6] = v.z; d[9] = v.w;
  }
  __syncthreads();
  const int lane = t & 63, wv = t >> 6;
  const int n16 = lane & 15, q = lane >> 4;
  // ---- conv1: MFMA 16x16x32, K=27(+pad), M=pixel col, N=32 oc ----
  {
    const bool isq1 = (q == 1), isq3 = (q == 3);
    const short8 wb0 = *(const short8*)(w1c + (((e * 2 + 0) * 4 + q) * 16 + n16) * 8);
    const short8 wb1 = *(const short8*)(w1c + (((e * 2 + 1) * 4 + q) * 16 + n16) * 8);
    const float bias0 = b1g[e * 32 + n16];
    const float bias1 = b1g[e * 32 + 16 + n16];
    int goff[4];
#pragma unroll
    for (int t4 = 0; t4 < 4; ++t4) {
      const int p0 = q * 8 + 2 * t4;
      const int r = (p0 * 939) >> 13;        // p0/9 for p0<32
      goff[t4] = r * 102 + (p0 - 9 * r);
    }
    for (int pid = 0; pid < 8; ++pid) {
      const int pairid = wv * 8 + pid;
      const int yp = pairid >> 1, xh = pairid & 1;
      const float* baseA = &xpi[(2 * yp) * 102 + (xh * 16 + n16) * 3];
      const short8 afA = gather_a(baseA, goff, isq1, isq3);
      const short8 afB = gather_a(baseA + 102, goff, isq1, isq3);
      f32x4 aA0 = {bias0, bias0, bias0, bias0}, aA1 = {bias1, bias1, bias1, bias1};
      f32x4 aB0 = aA0, aB1 = aA1;
      aA0 = __builtin_amdgcn_mfma_f32_16x16x32_bf16(afA, wb0, aA0, 0, 0, 0);
      aA1 = __builtin_amdgcn_mfma_f32_16x16x32_bf16(afA, wb1, aA1, 0, 0, 0);
      aB0 = __builtin_amdgcn_mfma_f32_16x16x32_bf16(afB, wb0, aB0, 0, 0, 0);
      aB1 = __builtin_amdgcn_mfma_f32_16x16x32_bf16(afB, wb1, aB1, 0, 0, 0);
      // 2x2 maxpool + relu -> h1s[pix][ic] bf16 (pixel stride 36)
      const int px = xh * 8 + 2 * q;
      unsigned short* hw = &h1s[((yp + 1) * 18 + (px + 1)) * 36];
      const float p00 = fmaxf(fmaxf(fmaxf(aA0[0], aA0[1]), fmaxf(aB0[0], aB0[1])), 0.f);
      const float p01 = fmaxf(fmaxf(fmaxf(aA0[2], aA0[3]), fmaxf(aB0[2], aB0[3])), 0.f);
      const float p10 = fmaxf(fmaxf(fmaxf(aA1[0], aA1[1]), fmaxf(aB1[0], aB1[1])), 0.f);
      const float p11 = fmaxf(fmaxf(fmaxf(aA1[2], aA1[3]), fmaxf(aB1[2], aB1[3])), 0.f);
      hw[n16]           = (unsigned short)f2bf(p00);
      hw[16 + n16]      = (unsigned short)f2bf(p10);
      hw[36 + n16]      = (unsigned short)f2bf(p01);
      hw[36 + 16 + n16] = (unsigned short)f2bf(p11);
    }
  }
  __syncthreads();
  // ---- conv2: wave = 4 rows x all 64 oc; B streamed from global (L2) with prefetch ----
  {
    const unsigned short* wbase = w2r + (size_t)e * 18432 + n16 * 32 + q * 8;
    float bz[4];
#pragma unroll
    for (int nt = 0; nt < 4; ++nt) bz[nt] = b2g[e * 64 + nt * 16 + n16];
    f32x4 acc[4][4];
#pragma unroll
    for (int mt4 = 0; mt4 < 4; ++mt4)
#pragma unroll
      for (int nt = 0; nt < 4; ++nt) {
        acc[mt4][nt][0] = bz[nt]; acc[mt4][nt][1] = bz[nt];
        acc[mt4][nt][2] = bz[nt]; acc[mt4][nt][3] = bz[nt];
      }
    short8 Bc[4];
#pragma unroll
    for (int nt = 0; nt < 4; ++nt) Bc[nt] = *(const short8*)(wbase + nt * 512);
#pragma unroll
    for (int s = 0; s < 9; ++s) {
      const int ky = s / 3, kx = s % 3;
      short8 Bn[4];
      if (s < 8) {
#pragma unroll
        for (int nt = 0; nt < 4; ++nt)
          Bn[nt] = *(const short8*)(wbase + (s + 1) * 2048 + nt * 512);
      }
#pragma unroll
      for (int mt4 = 0; mt4 < 4; ++mt4) {
        const int mt = wv * 4 + mt4;
        const short8 af = *(const short8*)&h1s[((mt + ky) * 18 + n16 + kx) * 36 + q * 8];
#pragma unroll
        for (int nt = 0; nt < 4; ++nt)
          acc[mt4][nt] = __builtin_amdgcn_mfma_f32_16x16x32_bf16(af, Bc[nt], acc[mt4][nt], 0, 0, 0);
      }
      if (s < 8) {
#pragma unroll
        for (int nt = 0; nt < 4; ++nt) Bc[nt] = Bn[nt];
      }
    }
    __syncthreads();                        // all MFMA reads of h1s done
    float* h2s = (float*)h1s;               // [oc][68]
#pragma unroll
    for (int u2 = 0; u2 < 2; ++u2) {
      const int py = wv * 2 + u2;
#pragma unroll
      for (int nt = 0; nt < 4; ++nt) {
        const f32x4 a = acc[2 * u2][nt], c = acc[2 * u2 + 1][nt];
        float2 pv;
        pv.x = fmaxf(fmaxf(fmaxf(a[0], a[1]), fmaxf(c[0], c[1])), 0.f);
        pv.y = fmaxf(fmaxf(fmaxf(a[2], a[3]), fmaxf(c[2], c[3])), 0.f);
        *(float2*)&h2s[(nt * 16 + n16) * 68 + py * 8 + 2 * q] = pv;
      }
    }
  }
  __syncthreads();
  {
    const float* h2s = (const float*)h1s;
    unsigned short* dst = h2b + (size_t)b * 4096;
#pragma unroll
    for (int j = 0; j < 2; ++j) {
      const int f = 8 * (t + 256 * j);          // flat k = oc*64+py*8+px
      const float* src = &h2s[(f >> 6) * 68 + (f & 63)];
      float4 v0 = *(const float4*)src;
      float4 v1 = *(const float4*)(src + 4);
      unsigned int p0 = pkbf(v0.x, v0.y);
      unsigned int p1 = pkbf(v0.z, v0.w);
      unsigned int p2 = pkbf(v1.x, v1.y);
      unsigned int p3 = pkbf(v1.z, v1.w);
      *(uint4*)(dst + f) = make_uint4(p0, p1, p2, p3);
    }
  }
}

// ---------------- K4: bucketed fc1, 512 threads / 8 waves (oc-split 16/wave) + aux ----------------
__global__ __launch_bounds__(512) void k_fc(const unsigned short* __restrict__ h2b,
    const unsigned short* __restrict__ w1r, const float* __restrict__ b1g,
    const float* __restrict__ w2g, const float* __restrict__ b2g,
    const int* __restrict__ counts, const int* __restrict__ order,
    const float* __restrict__ ew, float* __restrict__ outp) {
  const int bid = blockIdx.x;
  const int t = threadIdx.x;
  __shared__ float ax[4][4];
  if (bid == 0) {                            // aux loss (verbatim arithmetic, t<256)
    if (t < 256) {
      const float* pr = outp + 40960;        // probs_out
      float s0 = 0.f, s1 = 0.f, s2 = 0.f, s3 = 0.f;
      for (int i = t; i < 4096; i += 256) {
        const float4 v = *(const float4*)(pr + (size_t)i * 4);
        s0 += v.x; s1 += v.y; s2 += v.z; s3 += v.w;
      }
#pragma unroll
      for (int k = 1; k < 64; k <<= 1) {
        s0 += __shfl_xor(s0, k); s1 += __shfl_xor(s1, k);
        s2 += __shfl_xor(s2, k); s3 += __shfl_xor(s3, k);
      }
      if ((t & 63) == 0) {
        const int w = t >> 6;
        ax[w][0] = s0; ax[w][1] = s1; ax[w][2] = s2; ax[w][3] = s3;
      }
    }
    __syncthreads();
    if (t == 0) {
      float a = 0.f;
#pragma unroll
      for (int j = 0; j < 4; ++j) {
        const float mp = (ax[0][j] + ax[1][j] + ax[2][j] + ax[3][j]) * (1.f / 4096.f) - 0.25f;
        a += mp * mp;
      }
      outp[57344] = a * 0.25f;
    }
  }
  const int e = bid >> 8, tile = bid & 255;
  const int n = counts[e];
  const int base = tile * 16;
  if (base >= n) return;
  __shared__ int sb[16];
  __shared__ float wgt[16];
  __shared__ __align__(16) unsigned short As[16][280];   // 16 x 256 k, stride 280 (bank-clean)
  __shared__ float f1s[16 * 132];
  if (t < 16) {
    const int idx = base + t;
    const int s = order[e * B_N + ((idx < n) ? idx : base)];
    sb[t] = s; wgt[t] = ew[s];
  }
  __syncthreads();
  const int lane = t & 63, wv = t >> 6;      // wv in [0,8)
  const int n16 = lane & 15, q = lane >> 4;
  const int oc = wv * 16 + n16;              // 8 waves x 16 oc = 128
  const unsigned short* wb = w1r + ((size_t)(e * 128 + oc)) * 4096 + q * 8;
  f32x4 acc = {0.f, 0.f, 0.f, 0.f};
  const int ldrow = t >> 5, ldseg = t & 31;  // 16 rows x 32 segs x 8 u16
  const unsigned short* asrc = h2b + (size_t)sb[ldrow] * 4096;
  uint4 r0 = *(const uint4*)(asrc + ldseg * 8);            // prefetch kc=0
  for (int kc = 0; kc < 4096; kc += 256) {
    *(uint4*)&As[ldrow][ldseg * 8] = r0;
    __syncthreads();
    if (kc + 256 < 4096) {                                 // prefetch next chunk (overlaps MFMA)
      r0 = *(const uint4*)(asrc + (kc + 256) + ldseg * 8);
    }
#pragma unroll
    for (int ks = 0; ks < 8; ++ks) {
      const short8 af = *(const short8*)&As[n16][ks * 32 + q * 8];   // A[m=n16][k]
      const short8 bf = *(const short8*)(wb + kc + ks * 32);         // B[k][n=oc]
      acc = __builtin_amdgcn_mfma_f32_16x16x32_bf16(af, bf, acc, 0, 0, 0);
    }
    __syncthreads();
  }
  // C layout: row m = q*4+r (sample), col = n16 (oc)
  const float bb = b1g[e * 128 + oc];
#pragma unroll
  for (int r = 0; r < 4; ++r) {
    const int m = q * 4 + r;
    f1s[m * 132 + oc] = fmaxf(acc[r] + bb, 0.f);
  }
  __syncthreads();
  int m = n - base; if (m > 16) m = 16;
  if (t < 160) {
    const int r = t / 10, o = t - r * 10;
    if (r < m) {
      const float* w2 = w2g + (e * 10 + o) * 128;
      float s = b2g[e * 10 + o];
#pragma unroll 8
      for (int c = 0; c < 128; ++c) s += f1s[r * 132 + c] * w2[c];
      outp[(size_t)sb[r] * 10 + o] = s * wgt[r];
    }
  }
}

extern "C" void kernel_launch(void* const* d_in, const int* in_sizes, int n_in,
                              void* d_out, int out_size, void* d_ws, size_t ws_size,
                              hipStream_t stream) {
  const float* x        = (const float*)d_in[0];
  const float* gw_conv  = (const float*)d_in[1];
  const float* gb_conv  = (const float*)d_in[2];
  const float* gw_fc    = (const float*)d_in[3];
  const float* gb_fc    = (const float*)d_in[4];
  const float* ew_conv1 = (const float*)d_in[5];
  const float* eb_conv1 = (const float*)d_in[6];
  const float* ew_conv2 = (const float*)d_in[7];
  const float* eb_conv2 = (const float*)d_in[8];
  const float* ew_fc1   = (const float*)d_in[9];
  const float* eb_fc1   = (const float*)d_in[10];
  const float* ew_fc2   = (const float*)d_in[11];
  const float* eb_fc2   = (const float*)d_in[12];
  float* out = (float*)d_out;
  float* ws  = (float*)d_ws;

  unsigned short* h2b = (unsigned short*)(ws + H2B_OFF);
  int*   eidx   = (int*)(ws + EIDX_OFF);
  float* ew     = ws + EW_OFF;
  int*   order  = (int*)(ws + ORDER_OFF);
  int*   counts = (int*)(ws + CNT_OFF);
  unsigned short* w2r = (unsigned short*)(ws + W2R_OFF);
  unsigned short* w1r = (unsigned short*)(ws + W1R_OFF);
  unsigned short* w1c = (unsigned short*)(ws + W1C_OFF);

  k_front<<<6448, 256, 0, stream>>>(x, gw_conv, gb_conv, gw_fc, gb_fc,
                                    ew_fc1, w1r, ew_conv2, w2r, ew_conv1, w1c,
                                    counts, out + 40960, ew, eidx);
  k_experts_conv<<<4096, 256, 0, stream>>>(x, w1c, eb_conv1, w2r, eb_conv2,
                                           eidx, h2b, counts, order);
  k_fc<<<1024, 512, 0, stream>>>(h2b, w1r, eb_fc1, ew_fc2, eb_fc2,
                                 counts, order, ew, out);
}

// Round 12
// 247.272 us; speedup vs baseline: 1.0718x; 1.0718x over previous
//
#include <hip/hip_runtime.h>
#include <hip/hip_bf16.h>
#include <cstdint>
#include <cstddef>

#define B_N 4096
typedef short short8 __attribute__((ext_vector_type(8)));
typedef float f32x4 __attribute__((ext_vector_type(4)));
typedef float f32x2 __attribute__((ext_vector_type(2)));

// ws layout (float units)
static constexpr size_t H2B_OFF    = 0;                                  // 4096*4096 ushort
static constexpr size_t POOLED_OFF = 8388608;
static constexpr size_t EIDX_OFF   = POOLED_OFF + (size_t)B_N * 16;
static constexpr size_t EW_OFF     = EIDX_OFF + B_N;                     // B f
static constexpr size_t ORDER_OFF  = EW_OFF + B_N;                       // 4*B int
static constexpr size_t CNT_OFF    = ORDER_OFF + (size_t)4 * B_N;        // 4 int
static constexpr size_t PSUM_OFF   = CNT_OFF + 4;
static constexpr size_t W2R_OFF    = PSUM_OFF + 4;                       // 73728 ushort
static constexpr size_t W1R_OFF    = W2R_OFF + 36864;                    // 2097152 ushort
static constexpr size_t W1C_OFF    = W1R_OFF + 1048576;                  // 4096 ushort

__device__ __forceinline__ unsigned int f2bf(float f) {
  unsigned int u = __float_as_uint(f);
  return (u + 0x7fffu + ((u >> 16) & 1u)) >> 16;   // RNE bf16
}
__device__ __forceinline__ unsigned int pkbf(float lo, float hi) {
  float2 f; f.x = lo; f.y = hi;
  __hip_bfloat162 b = __float22bfloat162_rn(f);     // v_cvt_pk_bf16_f32
  union { __hip_bfloat162 b; unsigned u; } c; c.b = b; return c.u;
}

// ---------------- K1: weight repacks ONLY (router fused into K3) ----------------
// Structure ledger (R5-R11): router-in-conv (this config) = 244.8 us total; router
// moved back to a parallel k_front path = 265 us (R11 — the 4096-block router costs
// ~75 us standalone vs ~45 us amortized against conv's idle VALU). Launch merges
// fail (R8 coop-corruption, R9 spin-collapse). 3 nodes, residue ~65 us, stable.
__global__ __launch_bounds__(256) void k_front(
    const float* __restrict__ wfc1, unsigned short* __restrict__ w1r,
    const float* __restrict__ wc2, unsigned short* __restrict__ w2r,
    const float* __restrict__ wc1, unsigned short* __restrict__ w1c,
    int* __restrict__ counts) {
  const int rb = blockIdx.x, t = threadIdx.x;
  if (rb < 2048) {
    const int i = rb * 256 + t;                    // float4 index
    const float4 v = ((const float4*)wfc1)[i];
    ushort4 u;
    u.x = (unsigned short)f2bf(v.x); u.y = (unsigned short)f2bf(v.y);
    u.z = (unsigned short)f2bf(v.z); u.w = (unsigned short)f2bf(v.w);
    *(ushort4*)(w1r + 4 * (size_t)i) = u;
  } else if (rb < 2336) {
    if (rb == 2048 && t < 8) counts[t] = 0;        // counts[4] (+legacy psum[4])
    const int i = (rb - 2048) * 256 + t;
    if (i < 4 * 9 * 64 * 32) {
      const int ic = i & 31, j = i >> 5;
      const int oc = j & 63, j2 = j >> 6;
      const int s = j2 % 9, e = j2 / 9;
      w2r[i] = (unsigned short)f2bf(wc2[(((size_t)e * 64 + oc) * 32 + ic) * 9 + s]);
    }
  } else {
    const int i = (rb - 2336) * 256 + t;           // [0, 4096)
    if (i < 4096) {
      const int j = i & 7, n16 = (i >> 3) & 15, q = (i >> 7) & 3, nt = (i >> 9) & 1, e = i >> 10;
      const int k = q * 8 + j;
      float v = 0.f;
      if (k < 27) {
        const int ky = k / 9, c = k % 9, kx = c / 3, ic = c % 3;
        v = wc1[((e * 32 + nt * 16 + n16) * 3 + ic) * 9 + ky * 3 + kx];
      }
      w1c[i] = (unsigned short)f2bf(v);
    }
  }
}

// ---- conv1 A-fragment gather from ic-interleaved fp32 image (packed bf16 cvt) ----
__device__ __forceinline__ short8 gather_a(const float* __restrict__ base,
                                           const int* goff, bool isq1, bool isq3) {
  const float a0 = base[goff[0]];
  float       a1 = base[goff[0] + 1];
  const float b0 = base[goff[1]], b1 = base[goff[1] + 1];
  const float c0 = base[goff[2]], c1 = base[goff[2] + 1];
  const float d0 = base[goff[3]], d1 = base[goff[3] + 1];
  a1 = isq1 ? base[102] : a1;          // patch: p=9 (row 1, c 0) for q==1 lanes
  union { unsigned u[4]; short8 s; } r;
  r.u[0] = pkbf(a0, a1);
  r.u[1] = pkbf(b0, isq3 ? 0.f : b1);  // p>=27 zero padding (q==3)
  r.u[2] = isq3 ? 0u : pkbf(c0, c1);
  r.u[3] = isq3 ? 0u : pkbf(d0, d1);
  return r.s;
}

// ---------------- K3: FUSED router (conv16+pool+fc+softmax+top1, packed fp32)
// + conv1 MFMA -> h1 bf16 LDS -> conv2 MFMA -> h2 bf16 (R10 best config)
// + T5 s_setprio around the conv2 MFMA cluster (phase-diverse blocks on each CU:
// router-VALU waves vs conv2-MFMA waves -> scheduler arbitration is real here) ----
__global__ __launch_bounds__(256, 3) void k_experts_conv(const float* __restrict__ x,
    const float* __restrict__ gw, const float* __restrict__ gb,
    const float* __restrict__ gwfc, const float* __restrict__ gbfc,
    const unsigned short* __restrict__ w1c, const float* __restrict__ b1g,
    const unsigned short* __restrict__ w2r, const float* __restrict__ b2g,
    unsigned short* __restrict__ h2b, float* __restrict__ probs_out,
    float* __restrict__ ewt, int* __restrict__ counts, int* __restrict__ order) {
  __shared__ __align__(16) float xpi[3572];                  // 14288 B
  __shared__ __align__(16) unsigned short h1s[18 * 18 * 36]; // 23328 B
  __shared__ float red[16 * 33];                             // 2112 B
  __shared__ float pooled_s[16];
  __shared__ int es;
  const int b = blockIdx.x, t = threadIdx.x;
  {
    uint4 z4 = make_uint4(0, 0, 0, 0);
    uint4* z1 = (uint4*)h1s;
    for (int i = t; i < 1458; i += 256) z1[i] = z4;
    uint4* z2 = (uint4*)xpi;
    for (int i = t; i < 893; i += 256) z2[i] = z4;
  }
  __syncthreads();
  const float4* x4 = (const float4*)(x + (size_t)b * 3072);
  for (int i = t; i < 768; i += 256) {
    float4 v = x4[i];
    int flat = i * 4, ic = flat >> 10, rem = flat & 1023, row = rem >> 5, col = rem & 31;
    float* d = &xpi[(row + 1) * 102 + (col + 1) * 3 + ic];
    d[0] = v.x; d[3] = v.y; d[6] = v.z; d[9] = v.w;
  }
  __syncthreads();
  // ---- fused router (packed fp32): values bit-identical to the scalar path ----
  {
    const int ty = t >> 4, tx = t & 15;
    f32x2 wp[3][4][3];
#pragma unroll
    for (int ic = 0; ic < 3; ++ic)
#pragma unroll
    for (int rr = 0; rr < 4; ++rr) {
      const float* p = &xpi[(2 * ty + rr) * 102 + (2 * tx) * 3 + ic];
      const float r0 = p[0], r1 = p[3], r2 = p[6], r3 = p[9];
      wp[ic][rr][0] = (f32x2){r0, r1};
      wp[ic][rr][1] = (f32x2){r1, r2};
      wp[ic][rr][2] = (f32x2){r2, r3};
    }
    float sums[16];
#pragma unroll
    for (int oc = 0; oc < 16; ++oc) {
      const float bias = gb[oc];
      f32x2 A0 = {bias, bias};   // (a00, a01)
      f32x2 A1 = {bias, bias};   // (a10, a11)
#pragma unroll
      for (int ic = 0; ic < 3; ++ic)
#pragma unroll
      for (int ky = 0; ky < 3; ++ky)
#pragma unroll
      for (int kx = 0; kx < 3; ++kx) {
        const float wv2 = gw[oc * 27 + ic * 9 + ky * 3 + kx];
        const f32x2 ws = {wv2, wv2};
        A0 = __builtin_elementwise_fma(wp[ic][ky][kx], ws, A0);      // v_pk_fma_f32
        A1 = __builtin_elementwise_fma(wp[ic][ky + 1][kx], ws, A1);
      }
      sums[oc] = fmaxf(A0.x, 0.f) + fmaxf(A0.y, 0.f) + fmaxf(A1.x, 0.f) + fmaxf(A1.y, 0.f);
    }
    const int rl = t & 63, wid = t >> 6;
#pragma unroll
    for (int oc = 0; oc < 16; ++oc) {
      float s = sums[oc];
      s += __shfl_xor(s, 1);
      s += __shfl_xor(s, 2);
      s += __shfl_xor(s, 4);
      sums[oc] = s;
    }
    if ((rl & 7) == 0) {
      const int slot = wid * 8 + (rl >> 3);
#pragma unroll
      for (int oc = 0; oc < 16; ++oc) red[oc * 33 + slot] = sums[oc];
    }
    __syncthreads();
    if (t < 16) {
      float s = 0.f;
#pragma unroll
      for (int i = 0; i < 32; ++i) s += red[t * 33 + i];
      pooled_s[t] = s * (1.f / 1024.f);
    }
    __syncthreads();
    if (t == 0) {   // verbatim per-sample router FC + softmax + top1 + bucketing
      float l[4];
#pragma unroll
      for (int j = 0; j < 4; ++j) {
        float s = gbfc[j];
#pragma unroll
        for (int i = 0; i < 16; ++i) s += pooled_s[i] * gwfc[j * 16 + i];
        l[j] = s;
      }
      const float mx = fmaxf(fmaxf(l[0], l[1]), fmaxf(l[2], l[3]));
      float ex[4], ssum = 0.f;
#pragma unroll
      for (int j = 0; j < 4; ++j) { ex[j] = expf(l[j] - mx); ssum += ex[j]; }
      const float inv = 1.f / ssum;
      float p[4];
#pragma unroll
      for (int j = 0; j < 4; ++j) p[j] = ex[j] * inv;
      *(float4*)(probs_out + (size_t)b * 4) = make_float4(p[0], p[1], p[2], p[3]);
      int em = 0; float pm = p[0];
#pragma unroll
      for (int j = 1; j < 4; ++j) if (p[j] > pm) { pm = p[j]; em = j; }
      ewt[b] = pm;
      const int slot = atomicAdd(&counts[em], 1);
      order[em * B_N + slot] = b;
      es = em;
    }
    __syncthreads();
  }
  const int e = __builtin_amdgcn_readfirstlane(es);
  const int lane = t & 63, wv = t >> 6;
  const int n16 = lane & 15, q = lane >> 4;
  // ---- conv1: MFMA 16x16x32, K=27(+pad) ----
  {
    const bool isq1 = (q == 1), isq3 = (q == 3);
    const short8 wb0 = *(const short8*)(w1c + (((e * 2 + 0) * 4 + q) * 16 + n16) * 8);
    const short8 wb1 = *(const short8*)(w1c + (((e * 2 + 1) * 4 + q) * 16 + n16) * 8);
    const float bias0 = b1g[e * 32 + n16];
    const float bias1 = b1g[e * 32 + 16 + n16];
    int goff[4];
#pragma unroll
    for (int t4 = 0; t4 < 4; ++t4) {
      const int p0 = q * 8 + 2 * t4;
      const int r = (p0 * 939) >> 13;        // p0/9 for p0<32
      goff[t4] = r * 102 + (p0 - 9 * r);
    }
    for (int pid = 0; pid < 8; ++pid) {
      const int pairid = wv * 8 + pid;
      const int yp = pairid >> 1, xh = pairid & 1;
      const float* baseA = &xpi[(2 * yp) * 102 + (xh * 16 + n16) * 3];
      const short8 afA = gather_a(baseA, goff, isq1, isq3);
      const short8 afB = gather_a(baseA + 102, goff, isq1, isq3);
      f32x4 aA0 = {bias0, bias0, bias0, bias0}, aA1 = {bias1, bias1, bias1, bias1};
      f32x4 aB0 = aA0, aB1 = aA1;
      aA0 = __builtin_amdgcn_mfma_f32_16x16x32_bf16(afA, wb0, aA0, 0, 0, 0);
      aA1 = __builtin_amdgcn_mfma_f32_16x16x32_bf16(afA, wb1, aA1, 0, 0, 0);
      aB0 = __builtin_amdgcn_mfma_f32_16x16x32_bf16(afB, wb0, aB0, 0, 0, 0);
      aB1 = __builtin_amdgcn_mfma_f32_16x16x32_bf16(afB, wb1, aB1, 0, 0, 0);
      const int px = xh * 8 + 2 * q;
      unsigned short* hw = &h1s[((yp + 1) * 18 + (px + 1)) * 36];
      const float p00 = fmaxf(fmaxf(fmaxf(aA0[0], aA0[1]), fmaxf(aB0[0], aB0[1])), 0.f);
      const float p01 = fmaxf(fmaxf(fmaxf(aA0[2], aA0[3]), fmaxf(aB0[2], aB0[3])), 0.f);
      const float p10 = fmaxf(fmaxf(fmaxf(aA1[0], aA1[1]), fmaxf(aB1[0], aB1[1])), 0.f);
      const float p11 = fmaxf(fmaxf(fmaxf(aA1[2], aA1[3]), fmaxf(aB1[2], aB1[3])), 0.f);
      hw[n16]           = (unsigned short)f2bf(p00);
      hw[16 + n16]      = (unsigned short)f2bf(p10);
      hw[36 + n16]      = (unsigned short)f2bf(p01);
      hw[36 + 16 + n16] = (unsigned short)f2bf(p11);
    }
  }
  __syncthreads();
  // ---- conv2: wave = 4 rows x all 64 oc; B streamed from global (L2) with prefetch ----
  {
    const unsigned short* wbase = w2r + (size_t)e * 18432 + n16 * 32 + q * 8;
    float bz[4];
#pragma unroll
    for (int nt = 0; nt < 4; ++nt) bz[nt] = b2g[e * 64 + nt * 16 + n16];
    f32x4 acc[4][4];
#pragma unroll
    for (int mt4 = 0; mt4 < 4; ++mt4)
#pragma unroll
      for (int nt = 0; nt < 4; ++nt) {
        acc[mt4][nt][0] = bz[nt]; acc[mt4][nt][1] = bz[nt];
        acc[mt4][nt][2] = bz[nt]; acc[mt4][nt][3] = bz[nt];
      }
    short8 Bc[4];
#pragma unroll
    for (int nt = 0; nt < 4; ++nt) Bc[nt] = *(const short8*)(wbase + nt * 512);
#pragma unroll
    for (int s = 0; s < 9; ++s) {
      const int ky = s / 3, kx = s % 3;
      short8 Bn[4];
      if (s < 8) {
#pragma unroll
        for (int nt = 0; nt < 4; ++nt)
          Bn[nt] = *(const short8*)(wbase + (s + 1) * 2048 + nt * 512);
      }
      __builtin_amdgcn_s_setprio(1);        // T5: favor the MFMA cluster
#pragma unroll
      for (int mt4 = 0; mt4 < 4; ++mt4) {
        const int mt = wv * 4 + mt4;
        const short8 af = *(const short8*)&h1s[((mt + ky) * 18 + n16 + kx) * 36 + q * 8];
#pragma unroll
        for (int nt = 0; nt < 4; ++nt)
          acc[mt4][nt] = __builtin_amdgcn_mfma_f32_16x16x32_bf16(af, Bc[nt], acc[mt4][nt], 0, 0, 0);
      }
      __builtin_amdgcn_s_setprio(0);
      if (s < 8) {
#pragma unroll
        for (int nt = 0; nt < 4; ++nt) Bc[nt] = Bn[nt];
      }
    }
    __syncthreads();                        // all MFMA reads of h1s done
    float* h2s = (float*)h1s;               // [oc][68]
#pragma unroll
    for (int u2 = 0; u2 < 2; ++u2) {
      const int py = wv * 2 + u2;
#pragma unroll
      for (int nt = 0; nt < 4; ++nt) {
        const f32x4 a = acc[2 * u2][nt], c = acc[2 * u2 + 1][nt];
        float2 pv;
        pv.x = fmaxf(fmaxf(fmaxf(a[0], a[1]), fmaxf(c[0], c[1])), 0.f);
        pv.y = fmaxf(fmaxf(fmaxf(a[2], a[3]), fmaxf(c[2], c[3])), 0.f);
        *(float2*)&h2s[(nt * 16 + n16) * 68 + py * 8 + 2 * q] = pv;
      }
    }
  }
  __syncthreads();
  {
    const float* h2s = (const float*)h1s;
    unsigned short* dst = h2b + (size_t)b * 4096;
#pragma unroll
    for (int j = 0; j < 2; ++j) {
      const int f = 8 * (t + 256 * j);          // flat k = oc*64+py*8+px
      const float* src = &h2s[(f >> 6) * 68 + (f & 63)];
      float4 v0 = *(const float4*)src;
      float4 v1 = *(const float4*)(src + 4);
      unsigned int p0 = pkbf(v0.x, v0.y);
      unsigned int p1 = pkbf(v0.z, v0.w);
      unsigned int p2 = pkbf(v1.x, v1.y);
      unsigned int p3 = pkbf(v1.z, v1.w);
      *(uint4*)(dst + f) = make_uint4(p0, p1, p2, p3);
    }
  }
}

// ---------------- K4: bucketed fc1, 512 threads / 8 waves (oc-split 16/wave) + aux
// + T5 setprio around the 8-MFMA ks cluster ----------------
__global__ __launch_bounds__(512) void k_fc(const unsigned short* __restrict__ h2b,
    const unsigned short* __restrict__ w1r, const float* __restrict__ b1g,
    const float* __restrict__ w2g, const float* __restrict__ b2g,
    const int* __restrict__ counts, const int* __restrict__ order,
    const float* __restrict__ ew, float* __restrict__ outp) {
  const int bid = blockIdx.x;
  const int t = threadIdx.x;
  __shared__ float ax[4][4];
  if (bid == 0) {                            // aux loss (verbatim arithmetic, t<256)
    if (t < 256) {
      const float* pr = outp + 40960;        // probs_out
      float s0 = 0.f, s1 = 0.f, s2 = 0.f, s3 = 0.f;
      for (int i = t; i < 4096; i += 256) {
        const float4 v = *(const float4*)(pr + (size_t)i * 4);
        s0 += v.x; s1 += v.y; s2 += v.z; s3 += v.w;
      }
#pragma unroll
      for (int k = 1; k < 64; k <<= 1) {
        s0 += __shfl_xor(s0, k); s1 += __shfl_xor(s1, k);
        s2 += __shfl_xor(s2, k); s3 += __shfl_xor(s3, k);
      }
      if ((t & 63) == 0) {
        const int w = t >> 6;
        ax[w][0] = s0; ax[w][1] = s1; ax[w][2] = s2; ax[w][3] = s3;
      }
    }
    __syncthreads();
    if (t == 0) {
      float a = 0.f;
#pragma unroll
      for (int j = 0; j < 4; ++j) {
        const float mp = (ax[0][j] + ax[1][j] + ax[2][j] + ax[3][j]) * (1.f / 4096.f) - 0.25f;
        a += mp * mp;
      }
      outp[57344] = a * 0.25f;
    }
  }
  const int e = bid >> 8, tile = bid & 255;
  const int n = counts[e];
  const int base = tile * 16;
  if (base >= n) return;
  __shared__ int sb[16];
  __shared__ float wgt[16];
  __shared__ __align__(16) unsigned short As[16][280];   // 16 x 256 k, stride 280 (bank-clean)
  __shared__ float f1s[16 * 132];
  if (t < 16) {
    const int idx = base + t;
    const int s = order[e * B_N + ((idx < n) ? idx : base)];
    sb[t] = s; wgt[t] = ew[s];
  }
  __syncthreads();
  const int lane = t & 63, wv = t >> 6;      // wv in [0,8)
  const int n16 = lane & 15, q = lane >> 4;
  const int oc = wv * 16 + n16;              // 8 waves x 16 oc = 128
  const unsigned short* wb = w1r + ((size_t)(e * 128 + oc)) * 4096 + q * 8;
  f32x4 acc = {0.f, 0.f, 0.f, 0.f};
  const int ldrow = t >> 5, ldseg = t & 31;  // 16 rows x 32 segs x 8 u16
  const unsigned short* asrc = h2b + (size_t)sb[ldrow] * 4096;
  uint4 r0 = *(const uint4*)(asrc + ldseg * 8);            // prefetch kc=0
  for (int kc = 0; kc < 4096; kc += 256) {
    *(uint4*)&As[ldrow][ldseg * 8] = r0;
    __syncthreads();
    if (kc + 256 < 4096) {                                 // prefetch next chunk (overlaps MFMA)
      r0 = *(const uint4*)(asrc + (kc + 256) + ldseg * 8);
    }
    __builtin_amdgcn_s_setprio(1);          // T5: favor the MFMA cluster
#pragma unroll
    for (int ks = 0; ks < 8; ++ks) {
      const short8 af = *(const short8*)&As[n16][ks * 32 + q * 8];   // A[m=n16][k]
      const short8 bf = *(const short8*)(wb + kc + ks * 32);         // B[k][n=oc]
      acc = __builtin_amdgcn_mfma_f32_16x16x32_bf16(af, bf, acc, 0, 0, 0);
    }
    __builtin_amdgcn_s_setprio(0);
    __syncthreads();
  }
  // C layout: row m = q*4+r (sample), col = n16 (oc)
  const float bb = b1g[e * 128 + oc];
#pragma unroll
  for (int r = 0; r < 4; ++r) {
    const int m = q * 4 + r;
    f1s[m * 132 + oc] = fmaxf(acc[r] + bb, 0.f);
  }
  __syncthreads();
  int m = n - base; if (m > 16) m = 16;
  if (t < 160) {
    const int r = t / 10, o = t - r * 10;
    if (r < m) {
      const float* w2 = w2g + (e * 10 + o) * 128;
      float s = b2g[e * 10 + o];
#pragma unroll 8
      for (int c = 0; c < 128; ++c) s += f1s[r * 132 + c] * w2[c];
      outp[(size_t)sb[r] * 10 + o] = s * wgt[r];
    }
  }
}

extern "C" void kernel_launch(void* const* d_in, const int* in_sizes, int n_in,
                              void* d_out, int out_size, void* d_ws, size_t ws_size,
                              hipStream_t stream) {
  const float* x        = (const float*)d_in[0];
  const float* gw_conv  = (const float*)d_in[1];
  const float* gb_conv  = (const float*)d_in[2];
  const float* gw_fc    = (const float*)d_in[3];
  const float* gb_fc    = (const float*)d_in[4];
  const float* ew_conv1 = (const float*)d_in[5];
  const float* eb_conv1 = (const float*)d_in[6];
  const float* ew_conv2 = (const float*)d_in[7];
  const float* eb_conv2 = (const float*)d_in[8];
  const float* ew_fc1   = (const float*)d_in[9];
  const float* eb_fc1   = (const float*)d_in[10];
  const float* ew_fc2   = (const float*)d_in[11];
  const float* eb_fc2   = (const float*)d_in[12];
  float* out = (float*)d_out;
  float* ws  = (float*)d_ws;

  unsigned short* h2b = (unsigned short*)(ws + H2B_OFF);
  float* ew     = ws + EW_OFF;
  int*   order  = (int*)(ws + ORDER_OFF);
  int*   counts = (int*)(ws + CNT_OFF);
  unsigned short* w2r = (unsigned short*)(ws + W2R_OFF);
  unsigned short* w1r = (unsigned short*)(ws + W1R_OFF);
  unsigned short* w1c = (unsigned short*)(ws + W1C_OFF);

  k_front<<<2352, 256, 0, stream>>>(ew_fc1, w1r, ew_conv2, w2r, ew_conv1, w1c, counts);
  k_experts_conv<<<4096, 256, 0, stream>>>(x, gw_conv, gb_conv, gw_fc, gb_fc,
                                           w1c, eb_conv1, w2r, eb_conv2, h2b,
                                           out + 40960, ew, counts, order);
  k_fc<<<1024, 512, 0, stream>>>(h2b, w1r, eb_fc1, ew_fc2, eb_fc2,
                                 counts, order, ew, out);
}

// Round 13
// 244.277 us; speedup vs baseline: 1.0850x; 1.0123x over previous
//
#include <hip/hip_runtime.h>
#include <hip/hip_bf16.h>
#include <cstdint>
#include <cstddef>

#define B_N 4096
typedef short short8 __attribute__((ext_vector_type(8)));
typedef float f32x4 __attribute__((ext_vector_type(4)));
typedef float f32x2 __attribute__((ext_vector_type(2)));

// ws layout (float units)
static constexpr size_t H2B_OFF    = 0;                                  // 4096*4096 ushort
static constexpr size_t POOLED_OFF = 8388608;
static constexpr size_t EIDX_OFF   = POOLED_OFF + (size_t)B_N * 16;
static constexpr size_t EW_OFF     = EIDX_OFF + B_N;                     // B f
static constexpr size_t ORDER_OFF  = EW_OFF + B_N;                       // 4*B int
static constexpr size_t CNT_OFF    = ORDER_OFF + (size_t)4 * B_N;        // 4 int
static constexpr size_t PSUM_OFF   = CNT_OFF + 4;
static constexpr size_t W2R_OFF    = PSUM_OFF + 4;                       // 73728 ushort
static constexpr size_t W1R_OFF    = W2R_OFF + 36864;                    // 2097152 ushort
static constexpr size_t W1C_OFF    = W1R_OFF + 1048576;                  // 4096 ushort

__device__ __forceinline__ unsigned int f2bf(float f) {
  unsigned int u = __float_as_uint(f);
  return (u + 0x7fffu + ((u >> 16) & 1u)) >> 16;   // RNE bf16
}
__device__ __forceinline__ unsigned int pkbf(float lo, float hi) {
  float2 f; f.x = lo; f.y = hi;
  __hip_bfloat162 b = __float22bfloat162_rn(f);     // v_cvt_pk_bf16_f32
  union { __hip_bfloat162 b; unsigned u; } c; c.b = b; return c.u;
}

// ---------------- K1: weight repacks ONLY (router fused into K3) ----------------
// FINAL CONFIG (session best, 244.8 us). Structure ledger (R0-R12):
//  - router-in-conv (here) = 244.8; router on a parallel k_front path = 265 (R11).
//  - conv occupancy is register-floored: ~148 live regs incl 64 AGPR acc ->
//    launch_bounds(256,3); any cap <=128 spills catastrophically (R1/R2/R4).
//  - launch merges fail: cooperative gg.sync corrupts under graph capture (R8);
//    ticket+spin-gate collapses on same-address atomic polling (R9). 3 nodes,
//    ~65 us harness residue (~22 us/node), stable across rounds.
//  - T5 setprio: null here (R12, matches m190). pk-FMA router: real VALU savings
//    but latency-bound dur barely moves (R7). k_fc M/thread shapes: all neutral.
__global__ __launch_bounds__(256) void k_front(
    const float* __restrict__ wfc1, unsigned short* __restrict__ w1r,
    const float* __restrict__ wc2, unsigned short* __restrict__ w2r,
    const float* __restrict__ wc1, unsigned short* __restrict__ w1c,
    int* __restrict__ counts) {
  const int rb = blockIdx.x, t = threadIdx.x;
  if (rb < 2048) {
    const int i = rb * 256 + t;                    // float4 index
    const float4 v = ((const float4*)wfc1)[i];
    ushort4 u;
    u.x = (unsigned short)f2bf(v.x); u.y = (unsigned short)f2bf(v.y);
    u.z = (unsigned short)f2bf(v.z); u.w = (unsigned short)f2bf(v.w);
    *(ushort4*)(w1r + 4 * (size_t)i) = u;
  } else if (rb < 2336) {
    if (rb == 2048 && t < 8) counts[t] = 0;        // counts[4] (+legacy psum[4])
    const int i = (rb - 2048) * 256 + t;
    if (i < 4 * 9 * 64 * 32) {
      const int ic = i & 31, j = i >> 5;
      const int oc = j & 63, j2 = j >> 6;
      const int s = j2 % 9, e = j2 / 9;
      w2r[i] = (unsigned short)f2bf(wc2[(((size_t)e * 64 + oc) * 32 + ic) * 9 + s]);
    }
  } else {
    const int i = (rb - 2336) * 256 + t;           // [0, 4096)
    if (i < 4096) {
      const int j = i & 7, n16 = (i >> 3) & 15, q = (i >> 7) & 3, nt = (i >> 9) & 1, e = i >> 10;
      const int k = q * 8 + j;
      float v = 0.f;
      if (k < 27) {
        const int ky = k / 9, c = k % 9, kx = c / 3, ic = c % 3;
        v = wc1[((e * 32 + nt * 16 + n16) * 3 + ic) * 9 + ky * 3 + kx];
      }
      w1c[i] = (unsigned short)f2bf(v);
    }
  }
}

// ---- conv1 A-fragment gather from ic-interleaved fp32 image (packed bf16 cvt) ----
__device__ __forceinline__ short8 gather_a(const float* __restrict__ base,
                                           const int* goff, bool isq1, bool isq3) {
  const float a0 = base[goff[0]];
  float       a1 = base[goff[0] + 1];
  const float b0 = base[goff[1]], b1 = base[goff[1] + 1];
  const float c0 = base[goff[2]], c1 = base[goff[2] + 1];
  const float d0 = base[goff[3]], d1 = base[goff[3] + 1];
  a1 = isq1 ? base[102] : a1;          // patch: p=9 (row 1, c 0) for q==1 lanes
  union { unsigned u[4]; short8 s; } r;
  r.u[0] = pkbf(a0, a1);
  r.u[1] = pkbf(b0, isq3 ? 0.f : b1);  // p>=27 zero padding (q==3)
  r.u[2] = isq3 ? 0u : pkbf(c0, c1);
  r.u[3] = isq3 ? 0u : pkbf(d0, d1);
  return r.s;
}

// ---------------- K3: FUSED router (conv16+pool+fc+softmax+top1, packed fp32)
// + conv1 MFMA -> h1 bf16 LDS -> conv2 MFMA -> h2 bf16 ----------------
__global__ __launch_bounds__(256, 3) void k_experts_conv(const float* __restrict__ x,
    const float* __restrict__ gw, const float* __restrict__ gb,
    const float* __restrict__ gwfc, const float* __restrict__ gbfc,
    const unsigned short* __restrict__ w1c, const float* __restrict__ b1g,
    const unsigned short* __restrict__ w2r, const float* __restrict__ b2g,
    unsigned short* __restrict__ h2b, float* __restrict__ probs_out,
    float* __restrict__ ewt, int* __restrict__ counts, int* __restrict__ order) {
  __shared__ __align__(16) float xpi[3572];                  // 14288 B
  __shared__ __align__(16) unsigned short h1s[18 * 18 * 36]; // 23328 B
  __shared__ float red[16 * 33];                             // 2112 B
  __shared__ float pooled_s[16];
  __shared__ int es;
  const int b = blockIdx.x, t = threadIdx.x;
  {
    uint4 z4 = make_uint4(0, 0, 0, 0);
    uint4* z1 = (uint4*)h1s;
    for (int i = t; i < 1458; i += 256) z1[i] = z4;
    uint4* z2 = (uint4*)xpi;
    for (int i = t; i < 893; i += 256) z2[i] = z4;
  }
  __syncthreads();
  const float4* x4 = (const float4*)(x + (size_t)b * 3072);
  for (int i = t; i < 768; i += 256) {
    float4 v = x4[i];
    int flat = i * 4, ic = flat >> 10, rem = flat & 1023, row = rem >> 5, col = rem & 31;
    float* d = &xpi[(row + 1) * 102 + (col + 1) * 3 + ic];
    d[0] = v.x; d[3] = v.y; d[6] = v.z; d[9] = v.w;
  }
  __syncthreads();
  // ---- fused router (packed fp32): values bit-identical to the scalar path ----
  {
    const int ty = t >> 4, tx = t & 15;
    f32x2 wp[3][4][3];
#pragma unroll
    for (int ic = 0; ic < 3; ++ic)
#pragma unroll
    for (int rr = 0; rr < 4; ++rr) {
      const float* p = &xpi[(2 * ty + rr) * 102 + (2 * tx) * 3 + ic];
      const float r0 = p[0], r1 = p[3], r2 = p[6], r3 = p[9];
      wp[ic][rr][0] = (f32x2){r0, r1};
      wp[ic][rr][1] = (f32x2){r1, r2};
      wp[ic][rr][2] = (f32x2){r2, r3};
    }
    float sums[16];
#pragma unroll
    for (int oc = 0; oc < 16; ++oc) {
      const float bias = gb[oc];
      f32x2 A0 = {bias, bias};   // (a00, a01)
      f32x2 A1 = {bias, bias};   // (a10, a11)
#pragma unroll
      for (int ic = 0; ic < 3; ++ic)
#pragma unroll
      for (int ky = 0; ky < 3; ++ky)
#pragma unroll
      for (int kx = 0; kx < 3; ++kx) {
        const float wv2 = gw[oc * 27 + ic * 9 + ky * 3 + kx];
        const f32x2 ws = {wv2, wv2};
        A0 = __builtin_elementwise_fma(wp[ic][ky][kx], ws, A0);      // v_pk_fma_f32
        A1 = __builtin_elementwise_fma(wp[ic][ky + 1][kx], ws, A1);
      }
      sums[oc] = fmaxf(A0.x, 0.f) + fmaxf(A0.y, 0.f) + fmaxf(A1.x, 0.f) + fmaxf(A1.y, 0.f);
    }
    const int rl = t & 63, wid = t >> 6;
#pragma unroll
    for (int oc = 0; oc < 16; ++oc) {
      float s = sums[oc];
      s += __shfl_xor(s, 1);
      s += __shfl_xor(s, 2);
      s += __shfl_xor(s, 4);
      sums[oc] = s;
    }
    if ((rl & 7) == 0) {
      const int slot = wid * 8 + (rl >> 3);
#pragma unroll
      for (int oc = 0; oc < 16; ++oc) red[oc * 33 + slot] = sums[oc];
    }
    __syncthreads();
    if (t < 16) {
      float s = 0.f;
#pragma unroll
      for (int i = 0; i < 32; ++i) s += red[t * 33 + i];
      pooled_s[t] = s * (1.f / 1024.f);
    }
    __syncthreads();
    if (t == 0) {   // verbatim per-sample router FC + softmax + top1 + bucketing
      float l[4];
#pragma unroll
      for (int j = 0; j < 4; ++j) {
        float s = gbfc[j];
#pragma unroll
        for (int i = 0; i < 16; ++i) s += pooled_s[i] * gwfc[j * 16 + i];
        l[j] = s;
      }
      const float mx = fmaxf(fmaxf(l[0], l[1]), fmaxf(l[2], l[3]));
      float ex[4], ssum = 0.f;
#pragma unroll
      for (int j = 0; j < 4; ++j) { ex[j] = expf(l[j] - mx); ssum += ex[j]; }
      const float inv = 1.f / ssum;
      float p[4];
#pragma unroll
      for (int j = 0; j < 4; ++j) p[j] = ex[j] * inv;
      *(float4*)(probs_out + (size_t)b * 4) = make_float4(p[0], p[1], p[2], p[3]);
      int em = 0; float pm = p[0];
#pragma unroll
      for (int j = 1; j < 4; ++j) if (p[j] > pm) { pm = p[j]; em = j; }
      ewt[b] = pm;
      const int slot = atomicAdd(&counts[em], 1);
      order[em * B_N + slot] = b;
      es = em;
    }
    __syncthreads();
  }
  const int e = __builtin_amdgcn_readfirstlane(es);
  const int lane = t & 63, wv = t >> 6;
  const int n16 = lane & 15, q = lane >> 4;
  // ---- conv1: MFMA 16x16x32, K=27(+pad) ----
  {
    const bool isq1 = (q == 1), isq3 = (q == 3);
    const short8 wb0 = *(const short8*)(w1c + (((e * 2 + 0) * 4 + q) * 16 + n16) * 8);
    const short8 wb1 = *(const short8*)(w1c + (((e * 2 + 1) * 4 + q) * 16 + n16) * 8);
    const float bias0 = b1g[e * 32 + n16];
    const float bias1 = b1g[e * 32 + 16 + n16];
    int goff[4];
#pragma unroll
    for (int t4 = 0; t4 < 4; ++t4) {
      const int p0 = q * 8 + 2 * t4;
      const int r = (p0 * 939) >> 13;        // p0/9 for p0<32
      goff[t4] = r * 102 + (p0 - 9 * r);
    }
    for (int pid = 0; pid < 8; ++pid) {
      const int pairid = wv * 8 + pid;
      const int yp = pairid >> 1, xh = pairid & 1;
      const float* baseA = &xpi[(2 * yp) * 102 + (xh * 16 + n16) * 3];
      const short8 afA = gather_a(baseA, goff, isq1, isq3);
      const short8 afB = gather_a(baseA + 102, goff, isq1, isq3);
      f32x4 aA0 = {bias0, bias0, bias0, bias0}, aA1 = {bias1, bias1, bias1, bias1};
      f32x4 aB0 = aA0, aB1 = aA1;
      aA0 = __builtin_amdgcn_mfma_f32_16x16x32_bf16(afA, wb0, aA0, 0, 0, 0);
      aA1 = __builtin_amdgcn_mfma_f32_16x16x32_bf16(afA, wb1, aA1, 0, 0, 0);
      aB0 = __builtin_amdgcn_mfma_f32_16x16x32_bf16(afB, wb0, aB0, 0, 0, 0);
      aB1 = __builtin_amdgcn_mfma_f32_16x16x32_bf16(afB, wb1, aB1, 0, 0, 0);
      const int px = xh * 8 + 2 * q;
      unsigned short* hw = &h1s[((yp + 1) * 18 + (px + 1)) * 36];
      const float p00 = fmaxf(fmaxf(fmaxf(aA0[0], aA0[1]), fmaxf(aB0[0], aB0[1])), 0.f);
      const float p01 = fmaxf(fmaxf(fmaxf(aA0[2], aA0[3]), fmaxf(aB0[2], aB0[3])), 0.f);
      const float p10 = fmaxf(fmaxf(fmaxf(aA1[0], aA1[1]), fmaxf(aB1[0], aB1[1])), 0.f);
      const float p11 = fmaxf(fmaxf(fmaxf(aA1[2], aA1[3]), fmaxf(aB1[2], aB1[3])), 0.f);
      hw[n16]           = (unsigned short)f2bf(p00);
      hw[16 + n16]      = (unsigned short)f2bf(p10);
      hw[36 + n16]      = (unsigned short)f2bf(p01);
      hw[36 + 16 + n16] = (unsigned short)f2bf(p11);
    }
  }
  __syncthreads();
  // ---- conv2: wave = 4 rows x all 64 oc; B streamed from global (L2) with prefetch ----
  {
    const unsigned short* wbase = w2r + (size_t)e * 18432 + n16 * 32 + q * 8;
    float bz[4];
#pragma unroll
    for (int nt = 0; nt < 4; ++nt) bz[nt] = b2g[e * 64 + nt * 16 + n16];
    f32x4 acc[4][4];
#pragma unroll
    for (int mt4 = 0; mt4 < 4; ++mt4)
#pragma unroll
      for (int nt = 0; nt < 4; ++nt) {
        acc[mt4][nt][0] = bz[nt]; acc[mt4][nt][1] = bz[nt];
        acc[mt4][nt][2] = bz[nt]; acc[mt4][nt][3] = bz[nt];
      }
    short8 Bc[4];
#pragma unroll
    for (int nt = 0; nt < 4; ++nt) Bc[nt] = *(const short8*)(wbase + nt * 512);
#pragma unroll
    for (int s = 0; s < 9; ++s) {
      const int ky = s / 3, kx = s % 3;
      short8 Bn[4];
      if (s < 8) {
#pragma unroll
        for (int nt = 0; nt < 4; ++nt)
          Bn[nt] = *(const short8*)(wbase + (s + 1) * 2048 + nt * 512);
      }
#pragma unroll
      for (int mt4 = 0; mt4 < 4; ++mt4) {
        const int mt = wv * 4 + mt4;
        const short8 af = *(const short8*)&h1s[((mt + ky) * 18 + n16 + kx) * 36 + q * 8];
#pragma unroll
        for (int nt = 0; nt < 4; ++nt)
          acc[mt4][nt] = __builtin_amdgcn_mfma_f32_16x16x32_bf16(af, Bc[nt], acc[mt4][nt], 0, 0, 0);
      }
      if (s < 8) {
#pragma unroll
        for (int nt = 0; nt < 4; ++nt) Bc[nt] = Bn[nt];
      }
    }
    __syncthreads();                        // all MFMA reads of h1s done
    float* h2s = (float*)h1s;               // [oc][68]
#pragma unroll
    for (int u2 = 0; u2 < 2; ++u2) {
      const int py = wv * 2 + u2;
#pragma unroll
      for (int nt = 0; nt < 4; ++nt) {
        const f32x4 a = acc[2 * u2][nt], c = acc[2 * u2 + 1][nt];
        float2 pv;
        pv.x = fmaxf(fmaxf(fmaxf(a[0], a[1]), fmaxf(c[0], c[1])), 0.f);
        pv.y = fmaxf(fmaxf(fmaxf(a[2], a[3]), fmaxf(c[2], c[3])), 0.f);
        *(float2*)&h2s[(nt * 16 + n16) * 68 + py * 8 + 2 * q] = pv;
      }
    }
  }
  __syncthreads();
  {
    const float* h2s = (const float*)h1s;
    unsigned short* dst = h2b + (size_t)b * 4096;
#pragma unroll
    for (int j = 0; j < 2; ++j) {
      const int f = 8 * (t + 256 * j);          // flat k = oc*64+py*8+px
      const float* src = &h2s[(f >> 6) * 68 + (f & 63)];
      float4 v0 = *(const float4*)src;
      float4 v1 = *(const float4*)(src + 4);
      unsigned int p0 = pkbf(v0.x, v0.y);
      unsigned int p1 = pkbf(v0.z, v0.w);
      unsigned int p2 = pkbf(v1.x, v1.y);
      unsigned int p3 = pkbf(v1.z, v1.w);
      *(uint4*)(dst + f) = make_uint4(p0, p1, p2, p3);
    }
  }
}

// ---------------- K4: bucketed fc1, 512 threads / 8 waves (oc-split 16/wave) + aux ----------------
__global__ __launch_bounds__(512) void k_fc(const unsigned short* __restrict__ h2b,
    const unsigned short* __restrict__ w1r, const float* __restrict__ b1g,
    const float* __restrict__ w2g, const float* __restrict__ b2g,
    const int* __restrict__ counts, const int* __restrict__ order,
    const float* __restrict__ ew, float* __restrict__ outp) {
  const int bid = blockIdx.x;
  const int t = threadIdx.x;
  __shared__ float ax[4][4];
  if (bid == 0) {                            // aux loss (verbatim arithmetic, t<256)
    if (t < 256) {
      const float* pr = outp + 40960;        // probs_out
      float s0 = 0.f, s1 = 0.f, s2 = 0.f, s3 = 0.f;
      for (int i = t; i < 4096; i += 256) {
        const float4 v = *(const float4*)(pr + (size_t)i * 4);
        s0 += v.x; s1 += v.y; s2 += v.z; s3 += v.w;
      }
#pragma unroll
      for (int k = 1; k < 64; k <<= 1) {
        s0 += __shfl_xor(s0, k); s1 += __shfl_xor(s1, k);
        s2 += __shfl_xor(s2, k); s3 += __shfl_xor(s3, k);
      }
      if ((t & 63) == 0) {
        const int w = t >> 6;
        ax[w][0] = s0; ax[w][1] = s1; ax[w][2] = s2; ax[w][3] = s3;
      }
    }
    __syncthreads();
    if (t == 0) {
      float a = 0.f;
#pragma unroll
      for (int j = 0; j < 4; ++j) {
        const float mp = (ax[0][j] + ax[1][j] + ax[2][j] + ax[3][j]) * (1.f / 4096.f) - 0.25f;
        a += mp * mp;
      }
      outp[57344] = a * 0.25f;
    }
  }
  const int e = bid >> 8, tile = bid & 255;
  const int n = counts[e];
  const int base = tile * 16;
  if (base >= n) return;
  __shared__ int sb[16];
  __shared__ float wgt[16];
  __shared__ __align__(16) unsigned short As[16][280];   // 16 x 256 k, stride 280 (bank-clean)
  __shared__ float f1s[16 * 132];
  if (t < 16) {
    const int idx = base + t;
    const int s = order[e * B_N + ((idx < n) ? idx : base)];
    sb[t] = s; wgt[t] = ew[s];
  }
  __syncthreads();
  const int lane = t & 63, wv = t >> 6;      // wv in [0,8)
  const int n16 = lane & 15, q = lane >> 4;
  const int oc = wv * 16 + n16;              // 8 waves x 16 oc = 128
  const unsigned short* wb = w1r + ((size_t)(e * 128 + oc)) * 4096 + q * 8;
  f32x4 acc = {0.f, 0.f, 0.f, 0.f};
  const int ldrow = t >> 5, ldseg = t & 31;  // 16 rows x 32 segs x 8 u16
  const unsigned short* asrc = h2b + (size_t)sb[ldrow] * 4096;
  uint4 r0 = *(const uint4*)(asrc + ldseg * 8);            // prefetch kc=0
  for (int kc = 0; kc < 4096; kc += 256) {
    *(uint4*)&As[ldrow][ldseg * 8] = r0;
    __syncthreads();
    if (kc + 256 < 4096) {                                 // prefetch next chunk (overlaps MFMA)
      r0 = *(const uint4*)(asrc + (kc + 256) + ldseg * 8);
    }
#pragma unroll
    for (int ks = 0; ks < 8; ++ks) {
      const short8 af = *(const short8*)&As[n16][ks * 32 + q * 8];   // A[m=n16][k]
      const short8 bf = *(const short8*)(wb + kc + ks * 32);         // B[k][n=oc]
      acc = __builtin_amdgcn_mfma_f32_16x16x32_bf16(af, bf, acc, 0, 0, 0);
    }
    __syncthreads();
  }
  // C layout: row m = q*4+r (sample), col = n16 (oc)
  const float bb = b1g[e * 128 + oc];
#pragma unroll
  for (int r = 0; r < 4; ++r) {
    const int m = q * 4 + r;
    f1s[m * 132 + oc] = fmaxf(acc[r] + bb, 0.f);
  }
  __syncthreads();
  int m = n - base; if (m > 16) m = 16;
  if (t < 160) {
    const int r = t / 10, o = t - r * 10;
    if (r < m) {
      const float* w2 = w2g + (e * 10 + o) * 128;
      float s = b2g[e * 10 + o];
#pragma unroll 8
      for (int c = 0; c < 128; ++c) s += f1s[r * 132 + c] * w2[c];
      outp[(size_t)sb[r] * 10 + o] = s * wgt[r];
    }
  }
}

extern "C" void kernel_launch(void* const* d_in, const int* in_sizes, int n_in,
                              void* d_out, int out_size, void* d_ws, size_t ws_size,
                              hipStream_t stream) {
  const float* x        = (const float*)d_in[0];
  const float* gw_conv  = (const float*)d_in[1];
  const float* gb_conv  = (const float*)d_in[2];
  const float* gw_fc    = (const float*)d_in[3];
  const float* gb_fc    = (const float*)d_in[4];
  const float* ew_conv1 = (const float*)d_in[5];
  const float* eb_conv1 = (const float*)d_in[6];
  const float* ew_conv2 = (const float*)d_in[7];
  const float* eb_conv2 = (const float*)d_in[8];
  const float* ew_fc1   = (const float*)d_in[9];
  const float* eb_fc1   = (const float*)d_in[10];
  const float* ew_fc2   = (const float*)d_in[11];
  const float* eb_fc2   = (const float*)d_in[12];
  float* out = (float*)d_out;
  float* ws  = (float*)d_ws;

  unsigned short* h2b = (unsigned short*)(ws + H2B_OFF);
  float* ew     = ws + EW_OFF;
  int*   order  = (int*)(ws + ORDER_OFF);
  int*   counts = (int*)(ws + CNT_OFF);
  unsigned short* w2r = (unsigned short*)(ws + W2R_OFF);
  unsigned short* w1r = (unsigned short*)(ws + W1R_OFF);
  unsigned short* w1c = (unsigned short*)(ws + W1C_OFF);

  k_front<<<2352, 256, 0, stream>>>(ew_fc1, w1r, ew_conv2, w2r, ew_conv1, w1c, counts);
  k_experts_conv<<<4096, 256, 0, stream>>>(x, gw_conv, gb_conv, gw_fc, gb_fc,
                                           w1c, eb_conv1, w2r, eb_conv2, h2b,
                                           out + 40960, ew, counts, order);
  k_fc<<<1024, 512, 0, stream>>>(h2b, w1r, eb_fc1, ew_fc2, eb_fc2,
                                 counts, order, ew, out);
}